// Round 1
// baseline (196.707 us; speedup 1.0000x reference)
//
#include <hip/hip_runtime.h>
#include <stdint.h>

// ---------------------------------------------------------------------------
// Fused causal self-attention block: qkv = x@Wqkv, RoPE(q,k), SDPA, out@Wout
// B=2 T=2048 C=1024 H=16 Dh=64.  bf16 MFMA compute, fp32 accum/softmax.
// ---------------------------------------------------------------------------

typedef __attribute__((ext_vector_type(8))) __bf16 bf16x8;
typedef __attribute__((ext_vector_type(4))) float f32x4;

#define MFMA16(a, b, c) __builtin_amdgcn_mfma_f32_16x16x32_bf16((a), (b), (c), 0, 0, 0)

__device__ __forceinline__ unsigned short f2bf(float f) {
    union { float f; unsigned u; } x; x.f = f;
    unsigned r = x.u + 0x7FFFu + ((x.u >> 16) & 1u);   // RNE
    return (unsigned short)(r >> 16);
}
__device__ __forceinline__ float bf2f(unsigned short h) {
    union { unsigned u; float f; } x; x.u = ((unsigned)h) << 16;
    return x.f;
}

// ------------------------------- cast x -> bf16 ----------------------------
__global__ void cast_f32_bf16(const float* __restrict__ src,
                              unsigned short* __restrict__ dst, int n4) {
    int i = blockIdx.x * 256 + threadIdx.x;
    if (i >= n4) return;
    float4 v = ((const float4*)src)[i];
    ushort4 o;
    o.x = f2bf(v.x); o.y = f2bf(v.y); o.z = f2bf(v.z); o.w = f2bf(v.w);
    ((ushort4*)dst)[i] = o;
}

// ---------------------- transpose+cast weight: [K][N] -> [N][K] bf16 -------
__global__ void transpose_cast(const float* __restrict__ src,
                               unsigned short* __restrict__ dst, int K, int N) {
    __shared__ float tile[32][33];
    int n0 = blockIdx.x * 32, k0 = blockIdx.y * 32;
    int r = threadIdx.x >> 5, c = threadIdx.x & 31;   // 8 rows x 32 cols
#pragma unroll
    for (int i = 0; i < 4; i++) {
        int kk = r + i * 8;
        tile[kk][c] = src[(size_t)(k0 + kk) * N + n0 + c];
    }
    __syncthreads();
#pragma unroll
    for (int i = 0; i < 4; i++) {
        int nn = r + i * 8;
        dst[(size_t)(n0 + nn) * K + k0 + c] = f2bf(tile[c][nn]);
    }
}

// ------------------------------ RoPE tables --------------------------------
__global__ void rope_tables(float* __restrict__ ct, float* __restrict__ st) {
    int i = blockIdx.x * 256 + threadIdx.x;   // 2048*32 entries
    int t = i >> 5, d = i & 31;
    float ex = (float)(2 * d) / 64.0f;
    float inv = powf(10000.0f, -ex);
    float a = (float)t * inv;
    ct[i] = cosf(a);
    st[i] = sinf(a);
}

// ------------------------------ RoPE apply (in-place on q,k) ---------------
__global__ void rope_apply(unsigned short* __restrict__ q,
                           unsigned short* __restrict__ k,
                           const float* __restrict__ ct,
                           const float* __restrict__ st) {
    int i = blockIdx.x * 256 + threadIdx.x;   // B*H*T*32 = 2M
    int d = i & 31;
    int t = (i >> 5) & 2047;
    int bh = i >> 16;
    size_t base = ((size_t)bh * 2048 + t) * 64;
    float c = ct[t * 32 + d], s = st[t * 32 + d];
    float q1 = bf2f(q[base + d]), q2 = bf2f(q[base + d + 32]);
    q[base + d]      = f2bf(q1 * c - q2 * s);
    q[base + d + 32] = f2bf(q2 * c + q1 * s);
    float k1 = bf2f(k[base + d]), k2 = bf2f(k[base + d + 32]);
    k[base + d]      = f2bf(k1 * c - k2 * s);
    k[base + d + 32] = f2bf(k2 * c + k1 * s);
}

// ------------------------------ GEMM: C = A @ Bt^T --------------------------
// A [M][K] bf16 row-major, Bt [N][K] bf16 (i.e. B transposed, K-contiguous).
// 128x128 tile, BK=64, 256 threads = 4 waves in 2x2, 16x16x32 MFMA.
// MODE 0: scatter epilogue -> q [B,H,T,Dh], k [B,H,T,Dh], v^T [B,H,Dh,T] (bf16)
// MODE 1: plain fp32 store [M][N]
template <int MODE>
__global__ __launch_bounds__(256) void gemm_bt(
    const unsigned short* __restrict__ A,
    const unsigned short* __restrict__ Bt,
    unsigned short* __restrict__ oq,
    unsigned short* __restrict__ ok,
    unsigned short* __restrict__ ovt,
    float* __restrict__ of,
    int M_, int N_, int K_) {
    __shared__ __attribute__((aligned(16))) unsigned short ldsA[128 * 64];
    __shared__ __attribute__((aligned(16))) unsigned short ldsB[128 * 64];
    const int tid = threadIdx.x;
    const int lane = tid & 63, wv = tid >> 6;
    const int wr = wv >> 1, wc = wv & 1;
    const int l15 = lane & 15, lg = lane >> 4;
    const int m0 = blockIdx.x * 128, n0 = blockIdx.y * 128;

    f32x4 acc[4][4] = {};

    const int nkt = K_ >> 6;
    for (int kt = 0; kt < nkt; kt++) {
        if (kt) __syncthreads();
        // stage A,B tiles: 128 rows x 128 bytes each, XOR-swizzled
#pragma unroll
        for (int i = 0; i < 4; i++) {
            int idx = tid + i * 256;
            int row = idx >> 3, ch = idx & 7;
            int sb = row * 128 + ((ch * 16) ^ ((row & 7) << 4));
            *(bf16x8*)((char*)ldsA + sb) =
                *(const bf16x8*)(A + (size_t)(m0 + row) * K_ + kt * 64 + ch * 8);
            *(bf16x8*)((char*)ldsB + sb) =
                *(const bf16x8*)(Bt + (size_t)(n0 + row) * K_ + kt * 64 + ch * 8);
        }
        __syncthreads();
#pragma unroll
        for (int ks = 0; ks < 2; ks++) {
            const int kb = ks * 64 + lg * 16;
            bf16x8 af[4], bfr[4];
#pragma unroll
            for (int mf = 0; mf < 4; mf++) {
                int row = wr * 64 + mf * 16 + l15;
                af[mf] = *(const bf16x8*)((const char*)ldsA + row * 128 +
                                          (kb ^ ((row & 7) << 4)));
            }
#pragma unroll
            for (int nf = 0; nf < 4; nf++) {
                int row = wc * 64 + nf * 16 + l15;
                bfr[nf] = *(const bf16x8*)((const char*)ldsB + row * 128 +
                                           (kb ^ ((row & 7) << 4)));
            }
#pragma unroll
            for (int mf = 0; mf < 4; mf++)
#pragma unroll
                for (int nf = 0; nf < 4; nf++)
                    acc[mf][nf] = MFMA16(af[mf], bfr[nf], acc[mf][nf]);
        }
    }

    // epilogue.  C/D layout: col = lane&15, row = (lane>>4)*4 + reg  [m89/m91]
#pragma unroll
    for (int mf = 0; mf < 4; mf++) {
#pragma unroll
        for (int nf = 0; nf < 4; nf++) {
#pragma unroll
            for (int j = 0; j < 4; j++) {
                int grow = m0 + wr * 64 + mf * 16 + lg * 4 + j;
                int gcol = n0 + wc * 64 + nf * 16 + l15;
                float v = acc[mf][nf][j];
                if (MODE == 0) {
                    int b = grow >> 11, t = grow & 2047;
                    int s = gcol >> 10, c = gcol & 1023;
                    int h = c >> 6, d = c & 63;
                    int hb = b * 16 + h;
                    unsigned short bv = f2bf(v);
                    if (s == 0)
                        oq[((size_t)hb * 2048 + t) * 64 + d] = bv;
                    else if (s == 1)
                        ok[((size_t)hb * 2048 + t) * 64 + d] = bv;
                    else
                        ovt[((size_t)hb * 64 + d) * 2048 + t] = bv;
                } else {
                    of[(size_t)grow * N_ + gcol] = v;
                }
            }
        }
    }
}

// ------------------------------ flash attention ----------------------------
// grid (T/128, B*H).  4 waves; wave w owns q rows [q0+32w, q0+32w+31].
// K tiles of 64 keys.  Q in regs, K/V^T staged in swizzled LDS, P via LDS.
__global__ __launch_bounds__(256) void attn_fwd(
    const unsigned short* __restrict__ Q,
    const unsigned short* __restrict__ K,
    const unsigned short* __restrict__ Vt,
    unsigned short* __restrict__ O) {
    __shared__ __attribute__((aligned(16))) char lds[32768];
    // [0,8K): K tile [64 key][64 d]  [8K,16K): V^T tile [64 d][64 key]
    // [16K,32K): P [128 qrow][64 key] (per-wave 32-row slices)
    const int tid = threadIdx.x, lane = tid & 63, wv = tid >> 6;
    const int l15 = lane & 15, lg = lane >> 4;
    const int qt = blockIdx.x, bh = blockIdx.y;
    const int q0 = qt * 128;
    const int b = bh >> 4, h = bh & 15;
    const unsigned short* Qh = Q + (size_t)bh * 2048 * 64;
    const unsigned short* Kh = K + (size_t)bh * 2048 * 64;
    const unsigned short* Vh = Vt + (size_t)bh * 64 * 2048;

    bf16x8 qa[2][2];
#pragma unroll
    for (int mf = 0; mf < 2; mf++)
#pragma unroll
        for (int ks = 0; ks < 2; ks++) {
            int row = q0 + wv * 32 + mf * 16 + l15;
            qa[mf][ks] = *(const bf16x8*)(Qh + (size_t)row * 64 + ks * 32 + lg * 8);
        }

    f32x4 oacc[2][4] = {};
    float mi[2][4], li[2][4];
#pragma unroll
    for (int mf = 0; mf < 2; mf++)
#pragma unroll
        for (int j = 0; j < 4; j++) { mi[mf][j] = -1e30f; li[mf][j] = 0.f; }

    const int nkt = (q0 >> 6) + 2;   // causal: keys <= q0+127
    for (int kt = 0; kt < nkt; kt++) {
        const int k0 = kt * 64;
        // stage K and V^T tiles (swizzled rows of 128B)
#pragma unroll
        for (int i = 0; i < 2; i++) {
            int idx = tid + i * 256;
            int row = idx >> 3, ch = idx & 7;
            int sb = row * 128 + ((ch * 16) ^ ((row & 7) << 4));
            *(bf16x8*)(lds + sb) =
                *(const bf16x8*)(Kh + (size_t)(k0 + row) * 64 + ch * 8);
            *(bf16x8*)(lds + 8192 + sb) =
                *(const bf16x8*)(Vh + (size_t)row * 2048 + k0 + ch * 8);
        }
        __syncthreads();
        if (k0 <= q0 + wv * 32 + 31) {   // wave has at least one unmasked row
            // S = Q K^T
            f32x4 s[2][4] = {};
#pragma unroll
            for (int ks = 0; ks < 2; ks++) {
                const int kbo = ks * 64 + lg * 16;
                bf16x8 kb[4];
#pragma unroll
                for (int nf = 0; nf < 4; nf++) {
                    int row = nf * 16 + l15;
                    kb[nf] = *(const bf16x8*)(lds + row * 128 +
                                              (kbo ^ ((row & 7) << 4)));
                }
#pragma unroll
                for (int mf = 0; mf < 2; mf++)
#pragma unroll
                    for (int nf = 0; nf < 4; nf++)
                        s[mf][nf] = MFMA16(qa[mf][ks], kb[nf], s[mf][nf]);
            }
            const bool need_mask = (k0 + 63 > q0 + wv * 32);
            // online softmax, row = q0+wv*32+mf*16+lg*4+j, col = k0+nf*16+l15
#pragma unroll
            for (int mf = 0; mf < 2; mf++) {
#pragma unroll
                for (int j = 0; j < 4; j++) {
                    const int grow = q0 + wv * 32 + mf * 16 + lg * 4 + j;
                    float pv[4];
                    float rmax = -1e30f;
#pragma unroll
                    for (int nf = 0; nf < 4; nf++) {
                        float v = s[mf][nf][j] * 0.125f;
                        if (need_mask && (k0 + nf * 16 + l15 > grow)) v = -1e30f;
                        pv[nf] = v;
                        rmax = fmaxf(rmax, v);
                    }
                    rmax = fmaxf(rmax, __shfl_xor(rmax, 1));
                    rmax = fmaxf(rmax, __shfl_xor(rmax, 2));
                    rmax = fmaxf(rmax, __shfl_xor(rmax, 4));
                    rmax = fmaxf(rmax, __shfl_xor(rmax, 8));
                    const float mnew = fmaxf(mi[mf][j], rmax);
                    const float alpha = __expf(mi[mf][j] - mnew);
                    mi[mf][j] = mnew;
                    float rsum = 0.f;
#pragma unroll
                    for (int nf = 0; nf < 4; nf++) {
                        float p = __expf(pv[nf] - mnew);
                        s[mf][nf][j] = p;
                        rsum += p;
                    }
                    rsum += __shfl_xor(rsum, 1);
                    rsum += __shfl_xor(rsum, 2);
                    rsum += __shfl_xor(rsum, 4);
                    rsum += __shfl_xor(rsum, 8);
                    li[mf][j] = li[mf][j] * alpha + rsum;
#pragma unroll
                    for (int df = 0; df < 4; df++) oacc[mf][df][j] *= alpha;
                }
            }
            // P -> LDS (bf16, swizzled); same-wave region -> in-order DS, no barrier
#pragma unroll
            for (int mf = 0; mf < 2; mf++)
#pragma unroll
                for (int nf = 0; nf < 4; nf++)
#pragma unroll
                    for (int j = 0; j < 4; j++) {
                        int rowl = wv * 32 + mf * 16 + lg * 4 + j;
                        int colb = (nf * 16 + l15) * 2;
                        *(unsigned short*)(lds + 16384 + rowl * 128 +
                                           (colb ^ ((rowl & 7) << 4))) =
                            f2bf(s[mf][nf][j]);
                    }
            // O += P @ V
#pragma unroll
            for (int ks = 0; ks < 2; ks++) {
                const int kbo = ks * 64 + lg * 16;
                bf16x8 pa[2], vb[4];
#pragma unroll
                for (int mf = 0; mf < 2; mf++) {
                    int rowp = wv * 32 + mf * 16 + l15;
                    pa[mf] = *(const bf16x8*)(lds + 16384 + rowp * 128 +
                                              (kbo ^ ((rowp & 7) << 4)));
                }
#pragma unroll
                for (int df = 0; df < 4; df++) {
                    int rowv = df * 16 + l15;
                    vb[df] = *(const bf16x8*)(lds + 8192 + rowv * 128 +
                                              (kbo ^ ((rowv & 7) << 4)));
                }
#pragma unroll
                for (int mf = 0; mf < 2; mf++)
#pragma unroll
                    for (int df = 0; df < 4; df++)
                        oacc[mf][df] = MFMA16(pa[mf], vb[df], oacc[mf][df]);
            }
        }
        __syncthreads();
    }
    // epilogue: write [B,T,C] bf16 (head h occupies cols h*64..h*64+63)
#pragma unroll
    for (int mf = 0; mf < 2; mf++)
#pragma unroll
        for (int j = 0; j < 4; j++) {
            int t = q0 + wv * 32 + mf * 16 + lg * 4 + j;
            float rl = 1.0f / li[mf][j];
#pragma unroll
            for (int df = 0; df < 4; df++) {
                int d = df * 16 + l15;
                O[((size_t)(b * 2048 + t)) * 1024 + h * 64 + d] =
                    f2bf(oacc[mf][df][j] * rl);
            }
        }
}

// ---------------------------------------------------------------------------
extern "C" void kernel_launch(void* const* d_in, const int* in_sizes, int n_in,
                              void* d_out, int out_size, void* d_ws, size_t ws_size,
                              hipStream_t stream) {
    const float* x     = (const float*)d_in[0];
    const float* w_qkv = (const float*)d_in[1];
    const float* w_out = (const float*)d_in[2];
    float* out = (float*)d_out;
    char* ws = (char*)d_ws;
    const size_t MB = 1024 * 1024;

    unsigned short* xb    = (unsigned short*)(ws);             //  8 MB [4096][1024]
    unsigned short* wqkvt = (unsigned short*)(ws + 8 * MB);    //  6 MB [3072][1024]
    unsigned short* woutt = (unsigned short*)(ws + 14 * MB);   //  2 MB [1024][1024]
    unsigned short* qh    = (unsigned short*)(ws + 16 * MB);   //  8 MB [B,H,T,Dh]
    unsigned short* kh    = (unsigned short*)(ws + 24 * MB);   //  8 MB [B,H,T,Dh]
    unsigned short* vt    = (unsigned short*)(ws + 32 * MB);   //  8 MB [B,H,Dh,T]
    unsigned short* ao    = (unsigned short*)(ws + 40 * MB);   //  8 MB [4096][1024]
    float* ctab = (float*)(ws + 48 * MB);                      // 256 KB
    float* stab = (float*)(ws + 48 * MB + 256 * 1024);         // 256 KB

    cast_f32_bf16<<<4096, 256, 0, stream>>>(x, xb, (4096 * 1024) / 4);
    transpose_cast<<<dim3(96, 32), 256, 0, stream>>>(w_qkv, wqkvt, 1024, 3072);
    transpose_cast<<<dim3(32, 32), 256, 0, stream>>>(w_out, woutt, 1024, 1024);
    rope_tables<<<256, 256, 0, stream>>>(ctab, stab);

    gemm_bt<0><<<dim3(32, 24), 256, 0, stream>>>(xb, wqkvt, qh, kh, vt, nullptr,
                                                 4096, 3072, 1024);
    rope_apply<<<8192, 256, 0, stream>>>(qh, kh, ctab, stab);
    attn_fwd<<<dim3(16, 32), 256, 0, stream>>>(qh, kh, vt, ao);
    gemm_bt<1><<<dim3(32, 8), 256, 0, stream>>>(ao, woutt, nullptr, nullptr,
                                                nullptr, out, 4096, 1024, 1024);
}

// Round 2
// 147.967 us; speedup vs baseline: 1.3294x; 1.3294x over previous
//
#include <hip/hip_runtime.h>
#include <stdint.h>

// ---------------------------------------------------------------------------
// Fused causal self-attention block: qkv = x@Wqkv, RoPE(q,k), SDPA, out@Wout
// B=2 T=2048 C=1024 H=16 Dh=64.  bf16 MFMA compute, fp32 accum/softmax.
// ---------------------------------------------------------------------------

typedef __attribute__((ext_vector_type(8))) __bf16 bf16x8;
typedef __attribute__((ext_vector_type(4))) __bf16 bf16x4;
typedef __attribute__((ext_vector_type(4))) float f32x4;

#define MFMA16(a, b, c) __builtin_amdgcn_mfma_f32_16x16x32_bf16((a), (b), (c), 0, 0, 0)

#define SWAIT_VM0()                                     \
    do {                                                \
        asm volatile("s_waitcnt vmcnt(0)" ::: "memory");\
        __builtin_amdgcn_sched_barrier(0);              \
    } while (0)
#define SWAIT_LGKM0()                                     \
    do {                                                  \
        asm volatile("s_waitcnt lgkmcnt(0)" ::: "memory");\
        __builtin_amdgcn_sched_barrier(0);                \
    } while (0)

__device__ __forceinline__ void gl_lds16(const void* g, void* l) {
    __builtin_amdgcn_global_load_lds(
        (const __attribute__((address_space(1))) void*)g,
        (__attribute__((address_space(3))) void*)l, 16, 0, 0);
}

__device__ __forceinline__ unsigned short f2bf(float f) {
    union { float f; unsigned u; } x; x.f = f;
    unsigned r = x.u + 0x7FFFu + ((x.u >> 16) & 1u);   // RNE
    return (unsigned short)(r >> 16);
}
__device__ __forceinline__ float bf2f(unsigned short h) {
    union { unsigned u; float f; } x; x.u = ((unsigned)h) << 16;
    return x.f;
}

// ------------------------------- cast x -> bf16 ----------------------------
__global__ void cast_f32_bf16(const float* __restrict__ src,
                              unsigned short* __restrict__ dst, int n4) {
    int i = blockIdx.x * 256 + threadIdx.x;
    if (i >= n4) return;
    float4 v = ((const float4*)src)[i];
    ushort4 o;
    o.x = f2bf(v.x); o.y = f2bf(v.y); o.z = f2bf(v.z); o.w = f2bf(v.w);
    ((ushort4*)dst)[i] = o;
}

// ---------------------- transpose+cast weight: [K][N] -> [N][K] bf16 -------
__global__ void transpose_cast(const float* __restrict__ src,
                               unsigned short* __restrict__ dst, int K, int N) {
    __shared__ float tile[32][33];
    int n0 = blockIdx.x * 32, k0 = blockIdx.y * 32;
    int r = threadIdx.x >> 5, c = threadIdx.x & 31;   // 8 rows x 32 cols
#pragma unroll
    for (int i = 0; i < 4; i++) {
        int kk = r + i * 8;
        tile[kk][c] = src[(size_t)(k0 + kk) * N + n0 + c];
    }
    __syncthreads();
#pragma unroll
    for (int i = 0; i < 4; i++) {
        int nn = r + i * 8;
        dst[(size_t)(n0 + nn) * K + k0 + c] = f2bf(tile[c][nn]);
    }
}

// ------------------------------ RoPE tables --------------------------------
__global__ void rope_tables(float* __restrict__ ct, float* __restrict__ st) {
    int i = blockIdx.x * 256 + threadIdx.x;   // 2048*32 entries
    int t = i >> 5, d = i & 31;
    float ex = (float)(2 * d) / 64.0f;
    float inv = powf(10000.0f, -ex);
    float a = (float)t * inv;
    ct[i] = cosf(a);
    st[i] = sinf(a);
}

// ---------------- RoPE apply (in-place). Q also folds softmax scale --------
// QSC = (1/sqrt(Dh)) * log2(e) so attn softmax can use exp2 directly.
__global__ void rope_apply(unsigned short* __restrict__ q,
                           unsigned short* __restrict__ k,
                           const float* __restrict__ ct,
                           const float* __restrict__ st) {
    const float QSC = 0.125f * 1.44269504f;
    int i = blockIdx.x * 256 + threadIdx.x;   // B*H*T*32 = 2M
    int d = i & 31;
    int t = (i >> 5) & 2047;
    int bh = i >> 16;
    size_t base = ((size_t)bh * 2048 + t) * 64;
    float c = ct[t * 32 + d], s = st[t * 32 + d];
    float q1 = bf2f(q[base + d]), q2 = bf2f(q[base + d + 32]);
    q[base + d]      = f2bf((q1 * c - q2 * s) * QSC);
    q[base + d + 32] = f2bf((q2 * c + q1 * s) * QSC);
    float k1 = bf2f(k[base + d]), k2 = bf2f(k[base + d + 32]);
    k[base + d]      = f2bf(k1 * c - k2 * s);
    k[base + d + 32] = f2bf(k2 * c + k1 * s);
}

// ------------------------------ GEMM: C = A @ Bt^T --------------------------
// A [M][K] bf16 row-major, Bt [N][K] bf16.  128x128 tile, BK=64, 4 waves.
// global_load_lds staging (16B) with pre-swizzled source; swizzled ds_read.
// MODE 0: scatter epilogue -> q [B,H,T,Dh], k [B,H,T,Dh], v^T [B,H,Dh,T]
// MODE 1: plain fp32 store [M][N]
template <int MODE>
__global__ __launch_bounds__(256) void gemm_bt(
    const unsigned short* __restrict__ A,
    const unsigned short* __restrict__ Bt,
    unsigned short* __restrict__ oq,
    unsigned short* __restrict__ ok,
    unsigned short* __restrict__ ovt,
    float* __restrict__ of,
    int M_, int N_, int K_) {
    __shared__ __attribute__((aligned(16))) unsigned short ldsA[128 * 64];
    __shared__ __attribute__((aligned(16))) unsigned short ldsB[128 * 64];
    const int tid = threadIdx.x;
    const int lane = tid & 63, wv = tid >> 6;
    const int wr = wv >> 1, wc = wv & 1;
    const int l15 = lane & 15, lg = lane >> 4;
    const int lrow = lane >> 3, lch = lane & 7;
    const int swz = (lch * 16) ^ (lrow << 4);
    const int m0 = blockIdx.x * 128, n0 = blockIdx.y * 128;
    const char* Ab = (const char*)A;
    const char* Bb = (const char*)Bt;
    const size_t rstride = (size_t)K_ * 2;

    f32x4 acc[4][4] = {};

    const int nkt = K_ >> 6;
    for (int kt = 0; kt < nkt; kt++) {
        if (kt) __syncthreads();
#pragma unroll
        for (int ii = 0; ii < 4; ii++) {
            int r0 = wv * 32 + ii * 8;
            gl_lds16(Ab + (size_t)(m0 + r0 + lrow) * rstride + kt * 128 + swz,
                     (char*)ldsA + r0 * 128);
            gl_lds16(Bb + (size_t)(n0 + r0 + lrow) * rstride + kt * 128 + swz,
                     (char*)ldsB + r0 * 128);
        }
        __syncthreads();   // compiler drains vmcnt(0) before s_barrier
#pragma unroll
        for (int ks = 0; ks < 2; ks++) {
            const int kb = ks * 64 + lg * 16;
            bf16x8 af[4], bfr[4];
#pragma unroll
            for (int mf = 0; mf < 4; mf++) {
                int row = wr * 64 + mf * 16 + l15;
                af[mf] = *(const bf16x8*)((const char*)ldsA + row * 128 +
                                          (kb ^ ((row & 7) << 4)));
            }
#pragma unroll
            for (int nf = 0; nf < 4; nf++) {
                int row = wc * 64 + nf * 16 + l15;
                bfr[nf] = *(const bf16x8*)((const char*)ldsB + row * 128 +
                                           (kb ^ ((row & 7) << 4)));
            }
#pragma unroll
            for (int mf = 0; mf < 4; mf++)
#pragma unroll
                for (int nf = 0; nf < 4; nf++)
                    acc[mf][nf] = MFMA16(af[mf], bfr[nf], acc[mf][nf]);
        }
    }

    // epilogue.  C/D layout: col = lane&15, row = (lane>>4)*4 + reg  [m89/m91]
#pragma unroll
    for (int mf = 0; mf < 4; mf++) {
#pragma unroll
        for (int nf = 0; nf < 4; nf++) {
#pragma unroll
            for (int j = 0; j < 4; j++) {
                int grow = m0 + wr * 64 + mf * 16 + lg * 4 + j;
                int gcol = n0 + wc * 64 + nf * 16 + l15;
                float v = acc[mf][nf][j];
                if (MODE == 0) {
                    int b = grow >> 11, t = grow & 2047;
                    int s = gcol >> 10, c = gcol & 1023;
                    int h = c >> 6, d = c & 63;
                    int hb = b * 16 + h;
                    unsigned short bv = f2bf(v);
                    if (s == 0)
                        oq[((size_t)hb * 2048 + t) * 64 + d] = bv;
                    else if (s == 1)
                        ok[((size_t)hb * 2048 + t) * 64 + d] = bv;
                    else
                        ovt[((size_t)hb * 64 + d) * 2048 + t] = bv;
                } else {
                    of[(size_t)grow * N_ + gcol] = v;
                }
            }
        }
    }
}

// ------------------------------ flash attention ----------------------------
// 512 blocks x 256 thr.  Each WAVE is independent (no barriers): owns one
// 32-row q-tile, stages its own 64-key K/V tiles via global_load_lds into a
// private 20KB LDS slice, prefetching tile k+1 under softmax.  Swapped QK^T
// (mfma(K,Q) -> S^T) makes the key reduction lane-local + 2 shfls.
// Block tile sets {i,63-i,31-i,32+i} (rotated by i&3) balance total work.
__global__ __launch_bounds__(256, 2) void attn_fwd(
    const unsigned short* __restrict__ Q,
    const unsigned short* __restrict__ K,
    const unsigned short* __restrict__ Vt,
    unsigned short* __restrict__ O) {
    __shared__ __attribute__((aligned(16))) char ldsKV[4][16384];
    __shared__ __attribute__((aligned(16))) char ldsP[4][4096];
    const int tid = threadIdx.x, lane = tid & 63, wv = tid >> 6;
    const int l15 = lane & 15, lg = lane >> 4;
    const int lrow = lane >> 3, lch = lane & 7;
    const int swz = (lch * 16) ^ (lrow << 4);

    // XCD-chunked swizzle: each XCD gets 64 consecutive swz ids = 4 full bh
    const int wg = blockIdx.x;                  // 0..511
    const int sz = (wg & 7) * 64 + (wg >> 3);
    const int i = sz & 15, bh = sz >> 4;
    const int b = bh >> 4, h = bh & 15;
    // balanced tile set with rotation
    const int wp = (wv + (i & 3)) & 3;
    const int jt = (wp == 0) ? i : (wp == 1) ? (63 - i) : (wp == 2) ? (31 - i)
                                                                    : (32 + i);
    const int q0 = jt * 32;
    const int nkt = (jt >> 1) + 1;

    char* Kb = ldsKV[wv];
    char* Vb = ldsKV[wv] + 8192;
    char* Pb = ldsP[wv];
    const unsigned short* Qh = Q + (size_t)bh * 2048 * 64;
    const char* Kg = (const char*)(K + (size_t)bh * 2048 * 64);
    const char* Vg = (const char*)(Vt + (size_t)bh * 64 * 2048);

    // Q fragments (also serve as MFMA B-operand: same register layout)
    bf16x8 qa[2][2];
#pragma unroll
    for (int mf = 0; mf < 2; mf++)
#pragma unroll
        for (int ks = 0; ks < 2; ks++)
            qa[mf][ks] = *(const bf16x8*)(Qh + (size_t)(q0 + mf * 16 + l15) * 64 +
                                          ks * 32 + lg * 8);

    auto stage = [&](int k0) {
        const char* kg = Kg + (size_t)k0 * 128;          // K rows contiguous
        const char* vg = Vg + (size_t)k0 * 2;            // V^T row stride 4096B
#pragma unroll
        for (int ii = 0; ii < 8; ii++) {
            gl_lds16(kg + (ii * 8 + lrow) * 128 + swz, Kb + ii * 1024);
            gl_lds16(vg + (size_t)(ii * 8 + lrow) * 4096 + swz, Vb + ii * 1024);
        }
    };

    f32x4 oacc[2][4] = {};
    float mi[2] = {-1e30f, -1e30f}, li[2] = {0.f, 0.f};

    stage(0);
    for (int kt = 0; kt < nkt; kt++) {
        const int k0 = kt * 64;
        SWAIT_VM0();                       // staged K/V tile landed
        bf16x8 kb[2][4], vb[2][4];
#pragma unroll
        for (int ks = 0; ks < 2; ks++)
#pragma unroll
            for (int nf = 0; nf < 4; nf++) {
                int row = nf * 16 + l15;
                kb[ks][nf] = *(const bf16x8*)(
                    Kb + row * 128 + ((ks * 64 + lg * 16) ^ ((row & 7) << 4)));
            }
#pragma unroll
        for (int ks = 0; ks < 2; ks++)
#pragma unroll
            for (int df = 0; df < 4; df++) {
                int row = df * 16 + l15;
                vb[ks][df] = *(const bf16x8*)(
                    Vb + row * 128 + ((ks * 64 + lg * 16) ^ ((row & 7) << 4)));
            }
        // S^T = K Q^T : out col(l15)=q-row, out row(lg*4+j)=key
        f32x4 s[2][4] = {};
#pragma unroll
        for (int ks = 0; ks < 2; ks++)
#pragma unroll
            for (int mf = 0; mf < 2; mf++)
#pragma unroll
                for (int nf = 0; nf < 4; nf++)
                    s[mf][nf] = MFMA16(kb[ks][nf], qa[mf][ks], s[mf][nf]);
        SWAIT_LGKM0();                     // all K/V frags drained to regs
        if (kt + 1 < nkt) stage(k0 + 64);  // prefetch overwrites K/V slice
        // ---- online softmax (values already in log2 domain via Q scale) ----
        const bool dm = (kt == nkt - 1);
#pragma unroll
        for (int mf = 0; mf < 2; mf++) {
            if (dm) {
                int qrow = q0 + mf * 16 + l15;
#pragma unroll
                for (int nf = 0; nf < 4; nf++)
#pragma unroll
                    for (int j = 0; j < 4; j++)
                        if (k0 + nf * 16 + lg * 4 + j > qrow)
                            s[mf][nf][j] = -1e30f;
            }
            float rmax = -1e30f;
#pragma unroll
            for (int nf = 0; nf < 4; nf++)
#pragma unroll
                for (int j = 0; j < 4; j++) rmax = fmaxf(rmax, s[mf][nf][j]);
            rmax = fmaxf(rmax, __shfl_xor(rmax, 16));
            rmax = fmaxf(rmax, __shfl_xor(rmax, 32));
            const float mnew = fmaxf(mi[mf], rmax);
            const float alpha = exp2f(mi[mf] - mnew);
            mi[mf] = mnew;
            float rsum = 0.f;
#pragma unroll
            for (int nf = 0; nf < 4; nf++) {
#pragma unroll
                for (int j = 0; j < 4; j++) {
                    float p = exp2f(s[mf][nf][j] - mnew);
                    s[mf][nf][j] = p;
                    rsum += p;
                }
            }
            rsum += __shfl_xor(rsum, 16);
            rsum += __shfl_xor(rsum, 32);
            li[mf] = li[mf] * alpha + rsum;
            // P pack -> LDS (rows mf*16+l15, keys nf*16+lg*4+0..3), swizzled
#pragma unroll
            for (int nf = 0; nf < 4; nf++) {
                bf16x4 pk;
#pragma unroll
                for (int j = 0; j < 4; j++) pk[j] = (__bf16)s[mf][nf][j];
                int row = mf * 16 + l15;
                *(bf16x4*)(Pb + row * 128 +
                           ((nf * 32 + lg * 8) ^ ((row & 7) << 4))) = pk;
            }
            // rescale O: alpha lives at lane l15=row; gather row lg*4+j
#pragma unroll
            for (int j = 0; j < 4; j++) {
                float aj = __shfl(alpha, lg * 4 + j);
#pragma unroll
                for (int df = 0; df < 4; df++) oacc[mf][df][j] *= aj;
            }
        }
        // ---- O += P @ V (same-wave DS in order: P writes precede reads) ----
#pragma unroll
        for (int ks = 0; ks < 2; ks++) {
            bf16x8 pa[2];
#pragma unroll
            for (int mf = 0; mf < 2; mf++) {
                int row = mf * 16 + l15;
                pa[mf] = *(const bf16x8*)(
                    Pb + row * 128 + ((ks * 64 + lg * 16) ^ ((row & 7) << 4)));
            }
#pragma unroll
            for (int mf = 0; mf < 2; mf++)
#pragma unroll
                for (int df = 0; df < 4; df++)
                    oacc[mf][df] = MFMA16(pa[mf], vb[ks][df], oacc[mf][df]);
        }
    }
    // epilogue: O[b,t,h*64+d];  li lives at lane l15=row -> gather
#pragma unroll
    for (int mf = 0; mf < 2; mf++)
#pragma unroll
        for (int j = 0; j < 4; j++) {
            float lj = __shfl(li[mf], lg * 4 + j);
            float rl = 1.0f / lj;
            int t = q0 + mf * 16 + lg * 4 + j;
#pragma unroll
            for (int df = 0; df < 4; df++) {
                int d = df * 16 + l15;
                O[((size_t)(b * 2048 + t)) * 1024 + h * 64 + d] =
                    f2bf(oacc[mf][df][j] * rl);
            }
        }
}

// ---------------------------------------------------------------------------
extern "C" void kernel_launch(void* const* d_in, const int* in_sizes, int n_in,
                              void* d_out, int out_size, void* d_ws, size_t ws_size,
                              hipStream_t stream) {
    const float* x     = (const float*)d_in[0];
    const float* w_qkv = (const float*)d_in[1];
    const float* w_out = (const float*)d_in[2];
    float* out = (float*)d_out;
    char* ws = (char*)d_ws;
    const size_t MB = 1024 * 1024;

    unsigned short* xb    = (unsigned short*)(ws);             //  8 MB [4096][1024]
    unsigned short* wqkvt = (unsigned short*)(ws + 8 * MB);    //  6 MB [3072][1024]
    unsigned short* woutt = (unsigned short*)(ws + 14 * MB);   //  2 MB [1024][1024]
    unsigned short* qh    = (unsigned short*)(ws + 16 * MB);   //  8 MB [B,H,T,Dh]
    unsigned short* kh    = (unsigned short*)(ws + 24 * MB);   //  8 MB [B,H,T,Dh]
    unsigned short* vt    = (unsigned short*)(ws + 32 * MB);   //  8 MB [B,H,Dh,T]
    unsigned short* ao    = (unsigned short*)(ws + 40 * MB);   //  8 MB [4096][1024]
    float* ctab = (float*)(ws + 48 * MB);                      // 256 KB
    float* stab = (float*)(ws + 48 * MB + 256 * 1024);         // 256 KB

    cast_f32_bf16<<<4096, 256, 0, stream>>>(x, xb, (4096 * 1024) / 4);
    transpose_cast<<<dim3(96, 32), 256, 0, stream>>>(w_qkv, wqkvt, 1024, 3072);
    transpose_cast<<<dim3(32, 32), 256, 0, stream>>>(w_out, woutt, 1024, 1024);
    rope_tables<<<256, 256, 0, stream>>>(ctab, stab);

    gemm_bt<0><<<dim3(32, 24), 256, 0, stream>>>(xb, wqkvt, qh, kh, vt, nullptr,
                                                 4096, 3072, 1024);
    rope_apply<<<8192, 256, 0, stream>>>(qh, kh, ctab, stab);
    attn_fwd<<<512, 256, 0, stream>>>(qh, kh, vt, ao);
    gemm_bt<1><<<dim3(32, 8), 256, 0, stream>>>(ao, woutt, nullptr, nullptr,
                                                nullptr, out, 4096, 1024, 1024);
}